// Round 1
// 175.127 us; speedup vs baseline: 1.0295x; 1.0295x over previous
//
#include <hip/hip_runtime.h>
#include <hip/hip_bf16.h>

// LPLayer: e = x@W^T + b; lp = relu(tanh(e@e^T)); nf = lp@e / N
// B=8, N=2048, C_IN=128, D(C_OUT)=64. All I/O **fp32** (reference dtypes).
// d_out (float) = [nf (8*2048*64)] ++ [lp (8*2048*2048)]

#define B_    8
#define N_    2048
#define D_    64
#define CIN_  128

typedef __bf16 bf16x8 __attribute__((ext_vector_type(8)));
typedef float f32x4  __attribute__((ext_vector_type(4)));

union FragU { uint4 u; bf16x8 f; };

static __device__ __forceinline__ bf16x8 ld_frag(const __hip_bfloat16* p) {
    FragU fu; fu.u = *reinterpret_cast<const uint4*>(p); return fu.f;
}

static __device__ __forceinline__ void st_frag(__hip_bfloat16* p, bf16x8 f) {
    FragU fu; fu.f = f; *reinterpret_cast<uint4*>(p) = fu.u;
}

// Split 8 consecutive fp32 into hi/lo bf16x8 (hi = RTN(v), lo = RTN(v - hi)).
static __device__ __forceinline__ void split8(const float* p, bf16x8& hi, bf16x8& lo) {
    const float4 a = *reinterpret_cast<const float4*>(p);
    const float4 b = *reinterpret_cast<const float4*>(p + 4);
    const float v[8] = {a.x, a.y, a.z, a.w, b.x, b.y, b.z, b.w};
#pragma unroll
    for (int i = 0; i < 8; i++) {
        const __bf16 h = (__bf16)v[i];
        hi[i] = h;
        lo[i] = (__bf16)(v[i] - (float)h);
    }
}

// Convert 8 consecutive fp32 (LDS) to bf16x8.
static __device__ __forceinline__ bf16x8 cvt8(const float* p) {
    const float4 a = *reinterpret_cast<const float4*>(p);
    const float4 b = *reinterpret_cast<const float4*>(p + 4);
    bf16x8 r;
    r[0] = (__bf16)a.x; r[1] = (__bf16)a.y; r[2] = (__bf16)a.z; r[3] = (__bf16)a.w;
    r[4] = (__bf16)b.x; r[5] = (__bf16)b.y; r[6] = (__bf16)b.z; r[7] = (__bf16)b.w;
    return r;
}

// ---------------------------------------------------------------------------
// Kernel 1: e = x @ W^T + b (fp32 in), emit e_hi/e_lo (bf16 split) and
// e_hiT ([B][64][N] transposed bf16 for K2's PV B-operand).
// Split-MFMA: e = xh*wh + xh*wl + xl*wh  (error ~4e-6).
// Grid: 256 blocks x 256 thr (4 waves); wave = 16 rows x 64 chans.
// v2: W hi/lo split staged ONCE per block into LDS (was re-split per wave);
//     e_hiT stores packed 4x bf16 -> 8 B.
// ---------------------------------------------------------------------------
#define LDW  136  // W LDS row stride, bf16 elems (128 + 8 pad -> 2-way banks)

__global__ __launch_bounds__(256) void ex_kernel(
    const float* __restrict__ x,
    const float* __restrict__ W,
    const float* __restrict__ bias,
    __hip_bfloat16* __restrict__ e_hi,
    __hip_bfloat16* __restrict__ e_lo,
    __hip_bfloat16* __restrict__ e_hiT)
{
    __shared__ __align__(16) __hip_bfloat16 sW[2 * 64 * LDW];  // 34.8 KB
    __hip_bfloat16* sWhi = sW;
    __hip_bfloat16* sWlo = sW + 64 * LDW;

    const int tid  = threadIdx.x;

    // ---- stage W split into LDS: 64 rows x 128, 1024 chunks of 8 ----
#pragma unroll
    for (int p = 0; p < 4; p++) {
        const int q = tid + p * 256;
        const int r = q >> 4, c = (q & 15) * 8;
        bf16x8 hi, lo;
        split8(W + (size_t)r * CIN_ + c, hi, lo);
        st_frag(sWhi + r * LDW + c, hi);
        st_frag(sWlo + r * LDW + c, lo);
    }
    __syncthreads();

    const int w    = tid >> 6;
    const int lane = tid & 63;
    const int quad = lane >> 4;
    const int l16  = lane & 15;
    const int m0   = blockIdx.x * 64 + w * 16;   // 16 rows per wave

    // A-frags: A[m=lane&15][k=quad*8+j], 4 ksteps over K=128
    const float* xrow = x + (size_t)(m0 + l16) * CIN_;
    bf16x8 ah[4], al[4];
#pragma unroll
    for (int ks = 0; ks < 4; ks++)
        split8(xrow + ks * 32 + quad * 8, ah[ks], al[ks]);

    f32x4 acc[4];
#pragma unroll
    for (int nt = 0; nt < 4; nt++) acc[nt] = f32x4{0.f, 0.f, 0.f, 0.f};

#pragma unroll
    for (int ks = 0; ks < 4; ks++) {
#pragma unroll
        for (int nt = 0; nt < 4; nt++) {
            bf16x8 wh = ld_frag(sWhi + (nt * 16 + l16) * LDW + ks * 32 + quad * 8);
            bf16x8 wl = ld_frag(sWlo + (nt * 16 + l16) * LDW + ks * 32 + quad * 8);
            acc[nt] = __builtin_amdgcn_mfma_f32_16x16x32_bf16(ah[ks], wh, acc[nt], 0, 0, 0);
            acc[nt] = __builtin_amdgcn_mfma_f32_16x16x32_bf16(ah[ks], wl, acc[nt], 0, 0, 0);
            acc[nt] = __builtin_amdgcn_mfma_f32_16x16x32_bf16(al[ks], wh, acc[nt], 0, 0, 0);
        }
    }

    // Epilogue: bias, hi/lo split, stores. C/D: col=lane&15 (chan), row=quad*4+reg.
#pragma unroll
    for (int nt = 0; nt < 4; nt++) {
        const int chan = nt * 16 + l16;
        const float bv = bias[chan];
        union { __hip_bfloat16 h[4]; uint2 u2; } hv;
#pragma unroll
        for (int i = 0; i < 4; i++) {
            const int gr = m0 + quad * 4 + i;          // global row in [0, B*N)
            const float e = acc[nt][i] + bv;
            const __hip_bfloat16 hi = __float2bfloat16(e);
            const __hip_bfloat16 lo = __float2bfloat16(e - __bfloat162float(hi));
            e_hi[(size_t)gr * D_ + chan] = hi;
            e_lo[(size_t)gr * D_ + chan] = lo;
            hv.h[i] = hi;
        }
        // 4 consecutive ir rows (quad*4..+3, same bt always) -> one 8 B store
        const int gr0 = m0 + quad * 4;
        const int bt = gr0 >> 11, ir = gr0 & (N_ - 1);
        *reinterpret_cast<uint2*>(e_hiT + ((size_t)bt * D_ + chan) * N_ + ir) = hv.u2;
    }
}

// ---------------------------------------------------------------------------
// Kernel 2: fused Gram + tanh/relu + fp32 lp store + PV accumulate + nf store.
// v2 occupancy restructure: i-tile 64 -> 32 rows, grid (8, 64) = 512 blocks,
// LDS 88 KB -> 71168 B  =>  2 blocks/CU (16 waves/CU, was 8). The two
// co-resident blocks mutually hide the per-barrier vmcnt(0) store/stage
// drains that serialized v1 (1 block/CU had nothing to overlap with).
// Wave w: row-group g=w>>2 (16 rows at i0+16g), col/k-quarter h=w&3 (32 of 128).
// Gram split: S = Ahi*Bhi + Ahi*Blo + Alo*Bhi (near-fp32 accuracy).
// PV: each wave accumulates O[16x64] over its k-quarter; 4-way h-reduce in
// the epilogue via LDS. lp/nf stores are nontemporal (write-once stream;
// keeps the 768 KB/batch E panels resident in the XCD's 4 MB L2).
// ---------------------------------------------------------------------------
#define LDE  72   // E tile LDS row stride, bf16 elems (64 + 8 pad)
#define LDT  136  // EhiT LDS row stride, bf16 elems (128 + 8 pad)
#define LDF  132  // lp tile LDS row stride, fp32 elems (128 + 4 pad, 16B-mult)

__global__ __launch_bounds__(512, 4) void fused_kernel(
    const __hip_bfloat16* __restrict__ e_hi,
    const __hip_bfloat16* __restrict__ e_lo,
    const __hip_bfloat16* __restrict__ e_hiT,
    float* __restrict__ out)
{
    // 16896 + 18432 + 18432 + 17408 = 71168 B  (2 blocks/CU: 142336 <= 160K)
    __shared__ __align__(16) unsigned char smem[32 * LDF * 4 + 128 * LDE * 2 * 2 + 64 * LDT * 2];
    float*          sLpF  = (float*)smem;                           // [32][LDF] fp32
    __hip_bfloat16* sEhi  = (__hip_bfloat16*)(smem + 32 * LDF * 4); // [128][LDE]
    __hip_bfloat16* sElo  = sEhi + 128 * LDE;                       // [128][LDE]
    __hip_bfloat16* sEhiT = sElo + 128 * LDE;                       // [64][LDT]

    const int b   = blockIdx.x;          // batch (id%8: XCD-aligned)
    const int i0  = blockIdx.y * 32;
    const int tid = threadIdx.x;
    const int w = tid >> 6, lane = tid & 63, quad = lane >> 4, l16 = lane & 15;
    const int g = w >> 2, h = w & 3;
    const int m0 = i0 + g * 16;

    // Persistent A-frags: E_i rows (hi & lo), K=64 -> 2 ksteps
    const __hip_bfloat16* eih = e_hi + (size_t)(b * N_ + m0 + l16) * D_;
    const __hip_bfloat16* eil = e_lo + (size_t)(b * N_ + m0 + l16) * D_;
    bf16x8 ahi[2], alo[2];
#pragma unroll
    for (int ks = 0; ks < 2; ks++) {
        ahi[ks] = ld_frag(eih + ks * 32 + quad * 8);
        alo[ks] = ld_frag(eil + ks * 32 + quad * 8);
    }

    f32x4 o[4];
#pragma unroll
    for (int nt = 0; nt < 4; nt++) o[nt] = f32x4{0.f, 0.f, 0.f, 0.f};

    float* lp_out = out + (size_t)B_ * N_ * D_;

    for (int jt = 0; jt < 16; jt++) {
        const int j0 = jt * 128;
        __syncthreads();   // protect LDS from prior iteration's readers

        // ---- stage E_j (hi, lo, hiT) into LDS, coalesced 16B chunks ----
#pragma unroll
        for (int p = 0; p < 2; p++) {
            const int q = tid + p * 512;
            {   // Ehi/Elo: 128 rows x 64 ch = 1024 chunks
                const int r = q >> 3, c = (q & 7) * 8;
                *(uint4*)(sEhi + r * LDE + c) =
                    *(const uint4*)(e_hi + (size_t)(b * N_ + j0 + r) * D_ + c);
                *(uint4*)(sElo + r * LDE + c) =
                    *(const uint4*)(e_lo + (size_t)(b * N_ + j0 + r) * D_ + c);
            }
            {   // EhiT: 64 rows x 128 j = 1024 chunks
                const int r = q >> 4, c = (q & 15) * 8;
                *(uint4*)(sEhiT + r * LDT + c) =
                    *(const uint4*)(e_hiT + (size_t)(b * D_ + r) * N_ + j0 + c);
            }
        }
        __syncthreads();

        // ---- Gram: S[16 x 32] per wave, split product, tanh/relu -> sLpF ----
#pragma unroll
        for (int nt = 0; nt < 2; nt++) {
            const int n0 = h * 32 + nt * 16;
            f32x4 s = f32x4{0.f, 0.f, 0.f, 0.f};
#pragma unroll
            for (int ks = 0; ks < 2; ks++) {
                const int koff = ks * 32 + quad * 8;
                bf16x8 bhi = ld_frag(sEhi + (n0 + l16) * LDE + koff);
                bf16x8 blo = ld_frag(sElo + (n0 + l16) * LDE + koff);
                s = __builtin_amdgcn_mfma_f32_16x16x32_bf16(ahi[ks], bhi, s, 0, 0, 0);
                s = __builtin_amdgcn_mfma_f32_16x16x32_bf16(ahi[ks], blo, s, 0, 0, 0);
                s = __builtin_amdgcn_mfma_f32_16x16x32_bf16(alo[ks], bhi, s, 0, 0, 0);
            }
#pragma unroll
            for (int i = 0; i < 4; i++) {
                // relu(tanh(t)) = tanh(max(t,0)) — clamp BEFORE exp2: no
                // overflow path, and fmaxf(NaN,0)=0 absorbs upstream garbage.
                const float tc = fmaxf(s[i], 0.0f);
                const float z = __builtin_amdgcn_exp2f(tc * -2.8853900817779268f);
                const float v = (1.0f - z) * __builtin_amdgcn_rcpf(1.0f + z);
                const int row = g * 16 + quad * 4 + i;
                const int col = n0 + l16;
                sLpF[row * LDF + col] = v;
            }
        }
        __syncthreads();

        // ---- lp tile -> global fp32 FIRST (drain overlaps PV + next stage) ----
#pragma unroll
        for (int p = 0; p < 2; p++) {
            const int q = tid + p * 512;          // 0..1023
            const int r = q >> 5, c = (q & 31) * 4;
            __builtin_nontemporal_store(
                *(const f32x4*)(sLpF + r * LDF + c),
                (f32x4*)(lp_out + ((size_t)(b * N_ + i0 + r)) * N_ + j0 + c));
        }

        // ---- PV: O[16 x 64] += lp[16 x 32(quarter)] @ E_j[32(quarter) x 64ch] ----
        {
            const int koff = h * 32 + quad * 8;   // k = j within tile (wave's quarter)
            bf16x8 a = cvt8(sLpF + (g * 16 + l16) * LDF + koff);
#pragma unroll
            for (int nt = 0; nt < 4; nt++) {
                bf16x8 bfr = ld_frag(sEhiT + (nt * 16 + l16) * LDT + koff);
                o[nt] = __builtin_amdgcn_mfma_f32_16x16x32_bf16(a, bfr, o[nt], 0, 0, 0);
            }
        }
    }

    // ---- epilogue: sum 4 k-quarter partials, /N, store node_feats (fp32) ----
    __syncthreads();
    float* sO = (float*)smem;   // overlay (34.8 KB), all tile regions dead now
#pragma unroll
    for (int nt = 0; nt < 4; nt++) {
#pragma unroll
        for (int i = 0; i < 4; i++) {
            const int row = quad * 4 + i;            // local row in group
            const int chan = nt * 16 + l16;
            sO[w * 1088 + row * 68 + chan] = o[nt][i];   // stride 68: 2-way banks
        }
    }
    __syncthreads();
    {
        const int row = tid >> 4;                    // 0..31
        const int c4  = (tid & 15) * 4;
        const int gg = row >> 4, rr = row & 15;
        const float* base = sO + (gg * 4) * 1088 + rr * 68 + c4;
        const float4 v0 = *(const float4*)(base);
        const float4 v1 = *(const float4*)(base + 1088);
        const float4 v2 = *(const float4*)(base + 2176);
        const float4 v3 = *(const float4*)(base + 3264);
        f32x4 r;
        r[0] = (v0.x + v1.x + v2.x + v3.x) * (1.0f / 2048.0f);
        r[1] = (v0.y + v1.y + v2.y + v3.y) * (1.0f / 2048.0f);
        r[2] = (v0.z + v1.z + v2.z + v3.z) * (1.0f / 2048.0f);
        r[3] = (v0.w + v1.w + v2.w + v3.w) * (1.0f / 2048.0f);
        __builtin_nontemporal_store(
            r, (f32x4*)(out + ((size_t)(b * N_ + i0 + row)) * D_ + c4));
    }
}

// ---------------------------------------------------------------------------
extern "C" void kernel_launch(void* const* d_in, const int* in_sizes, int n_in,
                              void* d_out, int out_size, void* d_ws, size_t ws_size,
                              hipStream_t stream) {
    const float* x    = (const float*)d_in[0];
    const float* W    = (const float*)d_in[1];
    const float* bias = (const float*)d_in[2];
    float* out = (float*)d_out;

    __hip_bfloat16* e_hi  = (__hip_bfloat16*)d_ws;            // [B*N][64]
    __hip_bfloat16* e_lo  = e_hi + (size_t)B_ * N_ * D_;      // [B*N][64]
    __hip_bfloat16* e_hiT = e_lo + (size_t)B_ * N_ * D_;      // [B][64][N]

    ex_kernel<<<dim3(256), dim3(256), 0, stream>>>(x, W, bias, e_hi, e_lo, e_hiT);
    fused_kernel<<<dim3(8, 64), dim3(512), 0, stream>>>(e_hi, e_lo, e_hiT, out);
}